// Round 3
// baseline (317.293 us; speedup 1.0000x reference)
//
#include <hip/hip_runtime.h>
#include <hip/hip_bf16.h>

typedef __hip_bfloat16 bf16;
typedef __attribute__((ext_vector_type(8))) short bf16x8;   // 8 bf16 = 4 VGPRs
typedef __attribute__((ext_vector_type(4))) float f32x4;

constexpr int Bc  = 2;
constexpr int Sc  = 2048;
constexpr int Dc  = 1024;
constexpr int Hc  = 16;
constexpr int DHc = 64;
constexpr int BS  = Bc * Sc;   // 4096 rows
constexpr int NT  = Sc / 64;   // 32 key tiles

__device__ __forceinline__ float bs2f(unsigned short u) {
    union { unsigned int i; float f; } v; v.i = ((unsigned int)u) << 16; return v.f;
}
__device__ __forceinline__ short f2bs(float x) {
    bf16 h = __float2bfloat16(x);
    return *reinterpret_cast<short*>(&h);
}

// async global->LDS, 16B per lane. LDS dest is wave-uniform base + lane*16.
typedef const __attribute__((address_space(1))) unsigned int* as1_u32p;
typedef __attribute__((address_space(3))) unsigned int* as3_u32p;
__device__ __forceinline__ void gl_lds16(const void* g, void* l) {
    __builtin_amdgcn_global_load_lds((as1_u32p)g, (as3_u32p)l, 16, 0, 0);
}

// ---------------------------------------------------------------------------
// cast x (f32) -> bf16, same layout
// ---------------------------------------------------------------------------
__global__ __launch_bounds__(256) void cast_x(const float* __restrict__ in,
                                              short* __restrict__ out) {
    const int i = (blockIdx.x * 256 + threadIdx.x) * 4;
    const float4 v = *(const float4*)(in + i);
    ushort4 o;
    o.x = (unsigned short)f2bs(v.x);
    o.y = (unsigned short)f2bs(v.y);
    o.z = (unsigned short)f2bs(v.z);
    o.w = (unsigned short)f2bs(v.w);
    *(ushort4*)(out + i) = o;
}

// ---------------------------------------------------------------------------
// transpose + cast: in f32 [1024 k][1024 n] -> out bf16 [n][k].  z picks W.
// ---------------------------------------------------------------------------
__global__ __launch_bounds__(256) void transpose_cast(
    const float* __restrict__ w0, const float* __restrict__ w1,
    const float* __restrict__ w2, const float* __restrict__ w3,
    short* __restrict__ outbase)
{
    __shared__ float T[64][65];
    const int z = blockIdx.z;
    const float* in = (z == 0) ? w0 : (z == 1) ? w1 : (z == 2) ? w2 : w3;
    short* out = outbase + (size_t)z * 1024 * 1024;
    const int k0 = blockIdx.x * 64, n0 = blockIdx.y * 64;
    const int t = threadIdx.x;
    #pragma unroll
    for (int it = 0; it < 4; ++it) {
        const int s = it * 256 + t;
        const int r = s >> 4, c = (s & 15) * 4;
        *(float4*)&T[r][c] = *(const float4*)(in + (size_t)(k0 + r) * 1024 + n0 + c);
    }
    __syncthreads();
    #pragma unroll
    for (int it = 0; it < 4; ++it) {
        const int s = it * 256 + t;
        const int rr = s >> 4, cc = (s & 15) * 4;   // rr: n-local, cc: k-local
        ushort4 o;
        o.x = (unsigned short)f2bs(T[cc + 0][rr]);
        o.y = (unsigned short)f2bs(T[cc + 1][rr]);
        o.z = (unsigned short)f2bs(T[cc + 2][rr]);
        o.w = (unsigned short)f2bs(T[cc + 3][rr]);
        *(ushort4*)(out + (size_t)(n0 + rr) * 1024 + k0 + cc) = o;
    }
}

// ---------------------------------------------------------------------------
// MFMA GEMM (m97 structure): C[z] = A @ BT[z]^T + bias[z]
// 128x128 tile, BK=64, 256 thr = 4 waves of 64x64.
// ---------------------------------------------------------------------------
__global__ __launch_bounds__(256, 3) void gemm_bt(
    const short* __restrict__ A, const short* __restrict__ BTbase,
    const float* __restrict__ b0, const float* __restrict__ b1,
    const float* __restrict__ b2, short* __restrict__ Cbase)
{
    __shared__ __align__(16) short As[128 * 64];
    __shared__ __align__(16) short Bs[128 * 64];

    const int z = blockIdx.z;
    const short* BT = BTbase + (size_t)z * 1024 * 1024;
    const float* bias = (z == 0) ? b0 : (z == 1) ? b1 : b2;
    short* C = Cbase + (size_t)z * BS * Dc;

    const int t = threadIdx.x;
    const int lane = t & 63, w = t >> 6;
    const int quad = lane >> 4, l16 = lane & 15;
    const int wm = (w & 1) * 64, wn = (w >> 1) * 64;
    const int row0 = blockIdx.y * 128;
    const int col0 = blockIdx.x * 128;
    const int sw = l16 & 7;   // fragment-read swizzle key (row & 7)

    f32x4 acc[4][4] = {};

    for (int kt = 0; kt < 1024; kt += 64) {
        __syncthreads();
        #pragma unroll
        for (int i = 0; i < 4; ++i) {
            const int f = i * 256 + t;            // 16B slot index 0..1023
            const int r = f >> 3;                 // tile row 0..127
            const int g = (f & 7) ^ (r & 7);      // swizzled global seg
            short* lb = &As[(i * 256 + w * 64) * 8];   // wave-uniform base
            gl_lds16(A + (size_t)(row0 + r) * 1024 + kt + g * 8, lb);
            short* lb2 = &Bs[(i * 256 + w * 64) * 8];
            gl_lds16(BT + (size_t)(col0 + r) * 1024 + kt + g * 8, lb2);
        }
        __syncthreads();   // drains vmcnt before use
        #pragma unroll
        for (int ks = 0; ks < 2; ++ks) {
            bf16x8 av[4], bv[4];
            #pragma unroll
            for (int mt = 0; mt < 4; ++mt) {
                const int r = wm + mt * 16 + l16;
                av[mt] = *(const bf16x8*)&As[r * 64 + ((ks * 4 + quad) ^ sw) * 8];
            }
            #pragma unroll
            for (int nt = 0; nt < 4; ++nt) {
                const int r = wn + nt * 16 + l16;
                bv[nt] = *(const bf16x8*)&Bs[r * 64 + ((ks * 4 + quad) ^ sw) * 8];
            }
            #pragma unroll
            for (int mt = 0; mt < 4; ++mt)
                #pragma unroll
                for (int nt = 0; nt < 4; ++nt)
                    acc[mt][nt] = __builtin_amdgcn_mfma_f32_16x16x32_bf16(
                        av[mt], bv[nt], acc[mt][nt], 0, 0, 0);
        }
    }

    float bvv[4];
    #pragma unroll
    for (int nt = 0; nt < 4; ++nt) bvv[nt] = bias[col0 + wn + nt * 16 + l16];
    #pragma unroll
    for (int mt = 0; mt < 4; ++mt)
        #pragma unroll
        for (int reg = 0; reg < 4; ++reg) {
            const size_t row = row0 + wm + mt * 16 + quad * 4 + reg;
            #pragma unroll
            for (int nt = 0; nt < 4; ++nt) {
                const int col = col0 + wn + nt * 16 + l16;
                C[row * 1024 + col] = f2bs(acc[mt][nt][reg] + bvv[nt]);
            }
        }
}

// ---------------------------------------------------------------------------
// Key permutation pi(k) = (k&15)*4 + (k>>4), applied identically to the key
// axis of P and of VsT (sum over k is order-agnostic). Under pi, a thread's
// 4 P-values per output row become phys cols 4*l16+{0..3} -> one
// ds_write_b64 per row + packed cvt instead of 16 b16 writes + 16 RNE chains.
// ---------------------------------------------------------------------------

// softmax + P-publish + PV for one 16-row q-fragment given QK^T scores S.
// DIAG: only the diagonal tile applies the strict-upper (col > row) mask.
// C/D layout: row=quad*4+reg, col=l16.  A-frag A[m=l16][k=quad*8+j].
template<bool DIAG>
__device__ __forceinline__ void sm_pv(
    f32x4 (&S)[4],
    const short (&VsT)[64][72], short (&Psw)[16][72],
    const int k0, const int row_base,
    const int quad, const int l16,
    float (&l)[4], f32x4 (&O)[4])
{
    // exp(s/8) == exp2(s * 0.125*log2e); clamp 115.4 == old exp(<=80); mask
    // -126 -> 2^-126 ~= old exp(-87).
    #pragma unroll
    for (int nt = 0; nt < 4; ++nt) {
        #pragma unroll
        for (int reg = 0; reg < 4; ++reg) {
            float s = fminf(S[nt][reg] * 0.18033688f, 115.4f);
            if (DIAG) {
                const int col = k0 + nt * 16 + l16;
                const int row = row_base + quad * 4 + reg;
                s = (col > row) ? s : -126.0f;
            }
            const float p = exp2f(s);
            S[nt][reg] = p;
            l[reg] += p;
        }
    }

    // publish P: per output row, pack 4 values (phys cols 4*l16+0..3) -> b64
    #pragma unroll
    for (int reg = 0; reg < 4; ++reg) {
        const __hip_bfloat162 lo = __float22bfloat162_rn(make_float2(S[0][reg], S[1][reg]));
        const __hip_bfloat162 hi = __float22bfloat162_rn(make_float2(S[2][reg], S[3][reg]));
        uint2 u;
        u.x = *reinterpret_cast<const unsigned int*>(&lo);
        u.y = *reinterpret_cast<const unsigned int*>(&hi);
        *(uint2*)&Psw[quad * 4 + reg][l16 * 4] = u;
    }

    #pragma unroll
    for (int ks = 0; ks < 2; ++ks) {
        const bf16x8 pf = *(const bf16x8*)&Psw[l16][ks * 32 + quad * 8];
        #pragma unroll
        for (int nt = 0; nt < 4; ++nt) {
            const bf16x8 vf = *(const bf16x8*)&VsT[nt * 16 + l16][ks * 32 + quad * 8];
            O[nt] = __builtin_amdgcn_mfma_f32_16x16x32_bf16(pf, vf, O[nt], 0, 0, 0);
        }
    }
}

// ---------------------------------------------------------------------------
// Un-paired MFMA flash attention, strict-upper mask (attend j > i).
// 1024 blocks (alternating heavy/light q-tile map: consecutive dispatch
// indices sum to 33 iterations) x 256 thr = 4 waves -> 4 blocks/CU, 16
// waves/CU (vs 8 in R2: grid was the occupancy binder, not LDS).
// K is NOT staged in LDS: the QK^T B-fragment is a direct row-major global
// read, L2-resident (256 KB per (b,h)); fragments for tile t+1 load into
// the same registers right after the QK MFMAs consume them, hiding L2
// latency under softmax+PV+barrier. This removes ~10 KB/step of LDS-pipe
// traffic (the R2 pipe-model limiter) and shrinks LDS to 27.6 KB.
// V double-buffered in LDS (transposed, pi-permuted); one barrier per tile.
// Row S-1 (fully masked -> reference uniform softmax) fixed by vmean.
// ---------------------------------------------------------------------------
__global__ __launch_bounds__(256, 4) void attn_mfma(
    const short* __restrict__ Qg, const short* __restrict__ Kg,
    const short* __restrict__ Vg, short* __restrict__ CTX)
{
    __shared__ __align__(16) short VsT[2][64][72];   // [buf][d][pi(key)]
    __shared__ __align__(16) short Ps[4][16][72];    // per-wave P scratch

    const int tid  = threadIdx.x;
    const int lane = tid & 63, w = tid >> 6;         // w 0..3
    const int quad = lane >> 4, l16 = lane & 15;
    const int x  = blockIdx.x;                       // 0..31
    const int h  = blockIdx.y;
    const int b  = blockIdx.z;
    const size_t rb = (size_t)b * Sc;
    const int cb = h * DHc;

    const int myq = (x & 1) ? (NT - 1 - (x >> 1)) : (x >> 1);
    const int t0  = myq;
    const int q0  = myq * 64;

    // Q fragment for this wave's 16 rows
    bf16x8 qf[2];
    {
        const short* qp = Qg + (rb + q0 + w * 16 + l16) * (size_t)Dc + cb + quad * 8;
        qf[0] = *(const bf16x8*)(qp);
        qf[1] = *(const bf16x8*)(qp + 32);
    }
    float l[4] = {};
    f32x4 O[4] = {};

    // V staging: thread stages key row skey, d-segs sseg & sseg+32
    const int skey = tid & 63, sseg = (tid >> 6) * 8;
    const int pkey = ((skey & 15) << 2) | (skey >> 4);   // pi(skey)

    // K fragment registers (B-layout: lane(quad,l16) holds
    // K[key=nt*16+l16][d=ks*32+quad*8 .. +7]) -- direct global reads.
    bf16x8 kf[2][4];
    {
        const short* kp = Kg + (rb + t0 * 64 + l16) * (size_t)Dc + cb + quad * 8;
        #pragma unroll
        for (int ks = 0; ks < 2; ++ks)
            #pragma unroll
            for (int nt = 0; nt < 4; ++nt)
                kf[ks][nt] = *(const bf16x8*)(kp + (size_t)nt * 16 * Dc + ks * 32);
    }

    {   // stage first V tile t0 into buf t0&1
        const int buf = t0 & 1;
        const size_t g = (rb + t0 * 64 + skey) * (size_t)Dc + cb + sseg;
        const bf16x8 v0v = *(const bf16x8*)(Vg + g);
        const bf16x8 v1v = *(const bf16x8*)(Vg + g + 32);
        #pragma unroll
        for (int e = 0; e < 8; ++e) {
            VsT[buf][sseg + e][pkey]      = v0v[e];
            VsT[buf][sseg + 32 + e][pkey] = v1v[e];
        }
    }
    __syncthreads();

    for (int t = t0; t < NT; ++t) {
        const int cur = t & 1;
        const bool havenext = (t + 1 < NT);
        bf16x8 pv0, pv1;
        if (havenext) {   // register prefetch of V tile t+1
            const size_t g = (rb + (t + 1) * 64 + skey) * (size_t)Dc + cb + sseg;
            pv0 = *(const bf16x8*)(Vg + g);
            pv1 = *(const bf16x8*)(Vg + g + 32);
        }

        // QK^T
        f32x4 S[4] = {};
        #pragma unroll
        for (int ks = 0; ks < 2; ++ks)
            #pragma unroll
            for (int nt = 0; nt < 4; ++nt)
                S[nt] = __builtin_amdgcn_mfma_f32_16x16x32_bf16(qf[ks], kf[ks][nt], S[nt], 0, 0, 0);

        // reload kf with tile t+1 (regs free after MFMA issue; loads complete
        // during softmax+PV+barrier)
        if (havenext) {
            const short* kp = Kg + (rb + (t + 1) * 64 + l16) * (size_t)Dc + cb + quad * 8;
            #pragma unroll
            for (int ks = 0; ks < 2; ++ks)
                #pragma unroll
                for (int nt = 0; nt < 4; ++nt)
                    kf[ks][nt] = *(const bf16x8*)(kp + (size_t)nt * 16 * Dc + ks * 32);
        }

        if (t == t0)
            sm_pv<true >(S, VsT[cur], Ps[w], t * 64, q0 + w * 16, quad, l16, l, O);
        else
            sm_pv<false>(S, VsT[cur], Ps[w], t * 64, q0 + w * 16, quad, l16, l, O);

        if (havenext) {   // stage V tile t+1 into the other buffer, ONE barrier
            const int nb = cur ^ 1;
            #pragma unroll
            for (int e = 0; e < 8; ++e) {
                VsT[nb][sseg + e][pkey]      = pv0[e];
                VsT[nb][sseg + 32 + e][pkey] = pv1[e];
            }
            __syncthreads();
        }
    }

    // 16-lane reduction of l, then normalize + store
    #pragma unroll
    for (int off = 1; off < 16; off <<= 1)
        #pragma unroll
        for (int reg = 0; reg < 4; ++reg)
            l[reg] += __shfl_xor(l[reg], off, 64);
    #pragma unroll
    for (int reg = 0; reg < 4; ++reg) l[reg] = 1.0f / l[reg];
    #pragma unroll
    for (int nt = 0; nt < 4; ++nt)
        #pragma unroll
        for (int reg = 0; reg < 4; ++reg) {
            const size_t row = rb + q0 + w * 16 + quad * 4 + reg;
            CTX[row * Dc + cb + nt * 16 + l16] = f2bs(O[nt][reg] * l[reg]);
        }
}

// ---------------------------------------------------------------------------
// Row S-1 fully masked: reference softmax of all-(-1e9) is exactly uniform
// 1/S -> ctx = mean_j V[b,j,h,:]. Overwrites attn's placeholder.
// ---------------------------------------------------------------------------
__global__ __launch_bounds__(256) void vmean(const short* __restrict__ V,
                                             short* __restrict__ CTX)
{
    const int h = blockIdx.x, b = blockIdx.y;
    const int t = threadIdx.x;
    const int dh = t & 63, ck = t >> 6;      // 4 chunks of 512 keys
    float s = 0.f;
    const short* vp = V + ((size_t)b * Sc + ck * 512) * Dc + h * DHc + dh;
    for (int j = 0; j < 512; ++j) s += bs2f(vp[(size_t)j * Dc]);
    __shared__ float red[4][64];
    red[ck][dh] = s;
    __syncthreads();
    if (ck == 0) {
        const float tot = (red[0][dh] + red[1][dh] + red[2][dh] + red[3][dh]) * (1.f / Sc);
        CTX[((size_t)b * Sc + Sc - 1) * Dc + h * DHc + dh] = f2bs(tot);
    }
}

// ---------------------------------------------------------------------------
// out = LayerNorm(x + attn_out) * gamma + beta; x f32, AO bf16, out f32
// ---------------------------------------------------------------------------
__global__ __launch_bounds__(256, 4) void resid_ln(
    const float* __restrict__ X, const short* __restrict__ AO,
    const float* __restrict__ gamma, const float* __restrict__ beta,
    float* __restrict__ out)
{
    const int r = blockIdx.x;
    const int t = threadIdx.x;
    const size_t base = (size_t)r * Dc + t * 4;

    const float4 x4 = *(const float4*)(X + base);
    const ushort4 a4 = *(const ushort4*)(AO + base);
    float y[4];
    y[0] = x4.x + bs2f(a4.x);
    y[1] = x4.y + bs2f(a4.y);
    y[2] = x4.z + bs2f(a4.z);
    y[3] = x4.w + bs2f(a4.w);

    float s  = y[0] + y[1] + y[2] + y[3];
    float s2 = y[0]*y[0] + y[1]*y[1] + y[2]*y[2] + y[3]*y[3];
    #pragma unroll
    for (int off = 1; off < 64; off <<= 1) {
        s  += __shfl_xor(s,  off, 64);
        s2 += __shfl_xor(s2, off, 64);
    }
    __shared__ float red[8];
    const int w = t >> 6;
    if ((t & 63) == 0) { red[w] = s; red[4 + w] = s2; }
    __syncthreads();
    s  = red[0] + red[1] + red[2] + red[3];
    s2 = red[4] + red[5] + red[6] + red[7];

    const float mu   = s * (1.0f / Dc);
    const float rstd = rsqrtf(s2 * (1.0f / Dc) - mu * mu + 1e-6f);

    const float4 g4 = *(const float4*)(gamma + t * 4);
    const float4 b4 = *(const float4*)(beta  + t * 4);
    float4 o;
    o.x = (y[0] - mu) * rstd * g4.x + b4.x;
    o.y = (y[1] - mu) * rstd * g4.y + b4.y;
    o.z = (y[2] - mu) * rstd * g4.z + b4.z;
    o.w = (y[3] - mu) * rstd * g4.w + b4.w;
    *(float4*)(out + base) = o;
}

// ---------------------------------------------------------------------------
extern "C" void kernel_launch(void* const* d_in, const int* in_sizes, int n_in,
                              void* d_out, int out_size, void* d_ws, size_t ws_size,
                              hipStream_t stream)
{
    (void)in_sizes; (void)n_in; (void)out_size; (void)ws_size;
    const float* x     = (const float*)d_in[0];
    const float* Wq    = (const float*)d_in[1];
    const float* bq    = (const float*)d_in[2];
    const float* Wk    = (const float*)d_in[3];
    const float* bk    = (const float*)d_in[4];
    const float* Wv    = (const float*)d_in[5];
    const float* bv    = (const float*)d_in[6];
    const float* Wo    = (const float*)d_in[7];
    const float* bo    = (const float*)d_in[8];
    const float* gamma = (const float*)d_in[9];
    const float* beta  = (const float*)d_in[10];
    float* out = (float*)d_out;

    const size_t matN = (size_t)BS * Dc;       // 4,194,304
    const size_t wN   = (size_t)Dc * Dc;       // 1,048,576
    short* xb = (short*)d_ws;                  // 8 MB
    short* WT = xb + matN;                     // 8 MB (4 transposed weights)
    short* Qb = WT + 4 * wN;                   // 8 MB
    short* Kb = Qb + matN;                     // 8 MB
    short* Vb = Kb + matN;                     // 8 MB
    short* Cx = Vb + matN;                     // 8 MB
    short* AO = Qb;                            // Q dead after attention

    cast_x<<<matN / 1024, 256, 0, stream>>>(x, xb);

    dim3 gt(16, 16, 4);
    transpose_cast<<<gt, 256, 0, stream>>>(Wq, Wk, Wv, Wo, WT);

    dim3 gq(Dc / 128, BS / 128, 3);            // (8, 32, 3)
    gemm_bt<<<gq, 256, 0, stream>>>(xb, WT, bq, bk, bv, Qb);

    dim3 ga(32, Hc, Bc);                       // (32, 16, 2) un-paired q-tiles
    attn_mfma<<<ga, 256, 0, stream>>>(Qb, Kb, Vb, Cx);

    dim3 gv(Hc, Bc);
    vmean<<<gv, 256, 0, stream>>>(Vb, Cx);     // fix up row S-1 (uniform softmax)

    dim3 go(Dc / 128, BS / 128, 1);
    gemm_bt<<<go, 256, 0, stream>>>(Cx, WT + 3 * wN, bo, bo, bo, AO);

    resid_ln<<<BS, 256, 0, stream>>>(x, AO, gamma, beta, out);
}

// Round 4
// 238.877 us; speedup vs baseline: 1.3283x; 1.3283x over previous
//
#include <hip/hip_runtime.h>
#include <hip/hip_bf16.h>

typedef __hip_bfloat16 bf16;
typedef __attribute__((ext_vector_type(8))) short bf16x8;   // 8 bf16 = 4 VGPRs
typedef __attribute__((ext_vector_type(4))) float f32x4;

constexpr int Bc  = 2;
constexpr int Sc  = 2048;
constexpr int Dc  = 1024;
constexpr int Hc  = 16;
constexpr int DHc = 64;
constexpr int BS  = Bc * Sc;   // 4096 rows
constexpr int NT  = Sc / 64;   // 32 key tiles

__device__ __forceinline__ float bs2f(unsigned short u) {
    union { unsigned int i; float f; } v; v.i = ((unsigned int)u) << 16; return v.f;
}
__device__ __forceinline__ short f2bs(float x) {
    bf16 h = __float2bfloat16(x);
    return *reinterpret_cast<short*>(&h);
}

// async global->LDS, 16B per lane. LDS dest is wave-uniform base + lane*16.
typedef const __attribute__((address_space(1))) unsigned int* as1_u32p;
typedef __attribute__((address_space(3))) unsigned int* as3_u32p;
__device__ __forceinline__ void gl_lds16(const void* g, void* l) {
    __builtin_amdgcn_global_load_lds((as1_u32p)g, (as3_u32p)l, 16, 0, 0);
}

// ---------------------------------------------------------------------------
// cast x (f32) -> bf16, same layout
// ---------------------------------------------------------------------------
__global__ __launch_bounds__(256) void cast_x(const float* __restrict__ in,
                                              short* __restrict__ out) {
    const int i = (blockIdx.x * 256 + threadIdx.x) * 4;
    const float4 v = *(const float4*)(in + i);
    ushort4 o;
    o.x = (unsigned short)f2bs(v.x);
    o.y = (unsigned short)f2bs(v.y);
    o.z = (unsigned short)f2bs(v.z);
    o.w = (unsigned short)f2bs(v.w);
    *(ushort4*)(out + i) = o;
}

// ---------------------------------------------------------------------------
// transpose + cast: in f32 [1024 k][1024 n] -> out bf16 [n][k].  z picks W.
// ---------------------------------------------------------------------------
__global__ __launch_bounds__(256) void transpose_cast(
    const float* __restrict__ w0, const float* __restrict__ w1,
    const float* __restrict__ w2, const float* __restrict__ w3,
    short* __restrict__ outbase)
{
    __shared__ float T[64][65];
    const int z = blockIdx.z;
    const float* in = (z == 0) ? w0 : (z == 1) ? w1 : (z == 2) ? w2 : w3;
    short* out = outbase + (size_t)z * 1024 * 1024;
    const int k0 = blockIdx.x * 64, n0 = blockIdx.y * 64;
    const int t = threadIdx.x;
    #pragma unroll
    for (int it = 0; it < 4; ++it) {
        const int s = it * 256 + t;
        const int r = s >> 4, c = (s & 15) * 4;
        *(float4*)&T[r][c] = *(const float4*)(in + (size_t)(k0 + r) * 1024 + n0 + c);
    }
    __syncthreads();
    #pragma unroll
    for (int it = 0; it < 4; ++it) {
        const int s = it * 256 + t;
        const int rr = s >> 4, cc = (s & 15) * 4;   // rr: n-local, cc: k-local
        ushort4 o;
        o.x = (unsigned short)f2bs(T[cc + 0][rr]);
        o.y = (unsigned short)f2bs(T[cc + 1][rr]);
        o.z = (unsigned short)f2bs(T[cc + 2][rr]);
        o.w = (unsigned short)f2bs(T[cc + 3][rr]);
        *(ushort4*)(out + (size_t)(n0 + rr) * 1024 + k0 + cc) = o;
    }
}

// ---------------------------------------------------------------------------
// MFMA GEMM (m97 structure): C[z] = A @ BT[z]^T + bias[z]
// 128x128 tile, BK=64, 256 thr = 4 waves of 64x64.
// ---------------------------------------------------------------------------
__global__ __launch_bounds__(256, 3) void gemm_bt(
    const short* __restrict__ A, const short* __restrict__ BTbase,
    const float* __restrict__ b0, const float* __restrict__ b1,
    const float* __restrict__ b2, short* __restrict__ Cbase)
{
    __shared__ __align__(16) short As[128 * 64];
    __shared__ __align__(16) short Bs[128 * 64];

    const int z = blockIdx.z;
    const short* BT = BTbase + (size_t)z * 1024 * 1024;
    const float* bias = (z == 0) ? b0 : (z == 1) ? b1 : b2;
    short* C = Cbase + (size_t)z * BS * Dc;

    const int t = threadIdx.x;
    const int lane = t & 63, w = t >> 6;
    const int quad = lane >> 4, l16 = lane & 15;
    const int wm = (w & 1) * 64, wn = (w >> 1) * 64;
    const int row0 = blockIdx.y * 128;
    const int col0 = blockIdx.x * 128;
    const int sw = l16 & 7;   // fragment-read swizzle key (row & 7)

    f32x4 acc[4][4] = {};

    for (int kt = 0; kt < 1024; kt += 64) {
        __syncthreads();
        #pragma unroll
        for (int i = 0; i < 4; ++i) {
            const int f = i * 256 + t;            // 16B slot index 0..1023
            const int r = f >> 3;                 // tile row 0..127
            const int g = (f & 7) ^ (r & 7);      // swizzled global seg
            short* lb = &As[(i * 256 + w * 64) * 8];   // wave-uniform base
            gl_lds16(A + (size_t)(row0 + r) * 1024 + kt + g * 8, lb);
            short* lb2 = &Bs[(i * 256 + w * 64) * 8];
            gl_lds16(BT + (size_t)(col0 + r) * 1024 + kt + g * 8, lb2);
        }
        __syncthreads();   // drains vmcnt before use
        #pragma unroll
        for (int ks = 0; ks < 2; ++ks) {
            bf16x8 av[4], bv[4];
            #pragma unroll
            for (int mt = 0; mt < 4; ++mt) {
                const int r = wm + mt * 16 + l16;
                av[mt] = *(const bf16x8*)&As[r * 64 + ((ks * 4 + quad) ^ sw) * 8];
            }
            #pragma unroll
            for (int nt = 0; nt < 4; ++nt) {
                const int r = wn + nt * 16 + l16;
                bv[nt] = *(const bf16x8*)&Bs[r * 64 + ((ks * 4 + quad) ^ sw) * 8];
            }
            #pragma unroll
            for (int mt = 0; mt < 4; ++mt)
                #pragma unroll
                for (int nt = 0; nt < 4; ++nt)
                    acc[mt][nt] = __builtin_amdgcn_mfma_f32_16x16x32_bf16(
                        av[mt], bv[nt], acc[mt][nt], 0, 0, 0);
        }
    }

    float bvv[4];
    #pragma unroll
    for (int nt = 0; nt < 4; ++nt) bvv[nt] = bias[col0 + wn + nt * 16 + l16];
    #pragma unroll
    for (int mt = 0; mt < 4; ++mt)
        #pragma unroll
        for (int reg = 0; reg < 4; ++reg) {
            const size_t row = row0 + wm + mt * 16 + quad * 4 + reg;
            #pragma unroll
            for (int nt = 0; nt < 4; ++nt) {
                const int col = col0 + wn + nt * 16 + l16;
                C[row * 1024 + col] = f2bs(acc[mt][nt][reg] + bvv[nt]);
            }
        }
}

// ---------------------------------------------------------------------------
// Key permutation pi(k) = (k&15)*4 + (k>>4), applied identically to the key
// axis of P and of VsT (sum over k is order-agnostic). Under pi, a thread's
// 4 P-values per output row become phys cols 4*l16+{0..3} -> one
// ds_write_b64 per row + packed cvt instead of 16 b16 writes + 16 RNE chains.
// ---------------------------------------------------------------------------

// softmax(step) + PV for one 16-row q-fragment vs a staged 64-key tile.
// DIAG: only the diagonal tile applies the strict-upper (col > row) mask.
// Layouts (HW-validated): A-frag A[m=l16][k=quad*8+j]; B-frag
// B[k=quad*8+j][n=l16]; C/D row=quad*4+reg, col=l16.
template<bool DIAG>
__device__ __forceinline__ void qtile_step(
    const bf16x8 (&qf)[2],
    const short (&Ks)[64][72], const short (&VsT)[64][72],
    short (&Psw)[16][72],
    const int k0, const int row_base,
    const int quad, const int l16,
    float (&l)[4], f32x4 (&O)[4])
{
    bf16x8 kf[2][4];
    #pragma unroll
    for (int ks = 0; ks < 2; ++ks)
        #pragma unroll
        for (int nt = 0; nt < 4; ++nt)
            kf[ks][nt] = *(const bf16x8*)&Ks[nt * 16 + l16][ks * 32 + quad * 8];

    f32x4 S[4] = {};
    #pragma unroll
    for (int ks = 0; ks < 2; ++ks)
        #pragma unroll
        for (int nt = 0; nt < 4; ++nt)
            S[nt] = __builtin_amdgcn_mfma_f32_16x16x32_bf16(qf[ks], kf[ks][nt], S[nt], 0, 0, 0);

    // exp(s/8) == exp2(s * 0.125*log2e); clamp 115.4 == old exp(<=80); mask
    // -126 -> 2^-126 ~= old exp(-87).
    #pragma unroll
    for (int nt = 0; nt < 4; ++nt) {
        #pragma unroll
        for (int reg = 0; reg < 4; ++reg) {
            float s = fminf(S[nt][reg] * 0.18033688f, 115.4f);
            if (DIAG) {
                const int col = k0 + nt * 16 + l16;
                const int row = row_base + quad * 4 + reg;
                s = (col > row) ? s : -126.0f;
            }
            const float p = exp2f(s);
            S[nt][reg] = p;
            l[reg] += p;
        }
    }

    // publish P: per output row, pack 4 values (phys cols 4*l16+0..3) -> b64
    #pragma unroll
    for (int reg = 0; reg < 4; ++reg) {
        const __hip_bfloat162 lo = __float22bfloat162_rn(make_float2(S[0][reg], S[1][reg]));
        const __hip_bfloat162 hi = __float22bfloat162_rn(make_float2(S[2][reg], S[3][reg]));
        uint2 u;
        u.x = *reinterpret_cast<const unsigned int*>(&lo);
        u.y = *reinterpret_cast<const unsigned int*>(&hi);
        *(uint2*)&Psw[quad * 4 + reg][l16 * 4] = u;
    }

    #pragma unroll
    for (int ks = 0; ks < 2; ++ks) {
        const bf16x8 pf = *(const bf16x8*)&Psw[l16][ks * 32 + quad * 8];
        #pragma unroll
        for (int nt = 0; nt < 4; ++nt) {
            const bf16x8 vf = *(const bf16x8*)&VsT[nt * 16 + l16][ks * 32 + quad * 8];
            O[nt] = __builtin_amdgcn_mfma_f32_16x16x32_bf16(pf, vf, O[nt], 0, 0, 0);
        }
    }
}

// ---------------------------------------------------------------------------
// Un-paired MFMA flash attention, strict-upper mask (attend j > i).
// 1024 blocks x 256 thr (4 waves), K+V staged in LDS (R2 body: coalesced
// b128 staging, V pi-permuted+transposed, double-buffered, ONE barrier/tile).
// Occupancy fix vs R2: grid 1024 (not 512) + launch_bounds(256,3) with
// LDS 45KB -> 3 blocks/CU = 12 waves/CU.
// XCD remap: flat id f -> r=(f&7)*128+(f>>3). Under round-robin block->XCD
// dispatch each XCD owns 4 complete (b,h) groups; K/V/Q working set ~3MB
// fits its private 4MB L2 -> each (b,h) K/V fetched from HBM once, not 8x.
// Alternating heavy/light q-tile map keeps per-XCD load balanced.
// Row S-1 (fully masked -> reference uniform softmax) fixed by vmean.
// ---------------------------------------------------------------------------
__global__ __launch_bounds__(256, 3) void attn_mfma(
    const short* __restrict__ Qg, const short* __restrict__ Kg,
    const short* __restrict__ Vg, short* __restrict__ CTX)
{
    __shared__ __align__(16) short Ks [2][64][72];   // [buf][key][d]
    __shared__ __align__(16) short VsT[2][64][72];   // [buf][d][pi(key)]
    __shared__ __align__(16) short Ps[4][16][72];    // per-wave P scratch

    const int tid  = threadIdx.x;
    const int lane = tid & 63, w = tid >> 6;         // w 0..3
    const int quad = lane >> 4, l16 = lane & 15;

    // XCD-locality remap (bijective, 1024 % 8 == 0)
    const int f  = blockIdx.x + 32 * blockIdx.y + 512 * blockIdx.z;  // 0..1023
    const int r_ = (f & 7) * 128 + (f >> 3);
    const int xq = r_ & 31;
    const int h  = (r_ >> 5) & 15;
    const int b  = r_ >> 9;
    const size_t rb = (size_t)b * Sc;
    const int cb = h * DHc;

    const int myq = (xq & 1) ? (NT - 1 - (xq >> 1)) : (xq >> 1);
    const int t0  = myq;
    const int q0  = myq * 64;

    // Q fragment for this wave's 16 rows
    bf16x8 qf[2];
    {
        const short* qp = Qg + (rb + q0 + w * 16 + l16) * (size_t)Dc + cb + quad * 8;
        qf[0] = *(const bf16x8*)(qp);
        qf[1] = *(const bf16x8*)(qp + 32);
    }
    float l[4] = {};
    f32x4 O[4] = {};

    // staging: 256 threads; thread stages key row skey, d-segs sseg & sseg+32
    const int skey = tid & 63, sseg = (tid >> 6) * 8;
    const int pkey = ((skey & 15) << 2) | (skey >> 4);   // pi(skey)

    {   // stage first tile t0 into buf t0&1
        const int buf = t0 & 1;
        const size_t g = (rb + t0 * 64 + skey) * (size_t)Dc + cb + sseg;
        const bf16x8 k0v = *(const bf16x8*)(Kg + g);
        const bf16x8 k1v = *(const bf16x8*)(Kg + g + 32);
        const bf16x8 v0v = *(const bf16x8*)(Vg + g);
        const bf16x8 v1v = *(const bf16x8*)(Vg + g + 32);
        *(bf16x8*)&Ks[buf][skey][sseg]      = k0v;
        *(bf16x8*)&Ks[buf][skey][sseg + 32] = k1v;
        #pragma unroll
        for (int e = 0; e < 8; ++e) {
            VsT[buf][sseg + e][pkey]      = v0v[e];
            VsT[buf][sseg + 32 + e][pkey] = v1v[e];
        }
    }
    __syncthreads();

    for (int t = t0; t < NT; ++t) {
        const int cur = t & 1;
        const bool havenext = (t + 1 < NT);
        bf16x8 pk0, pk1, pv0, pv1;
        if (havenext) {   // register prefetch of tile t+1
            const size_t g = (rb + (t + 1) * 64 + skey) * (size_t)Dc + cb + sseg;
            pk0 = *(const bf16x8*)(Kg + g);
            pk1 = *(const bf16x8*)(Kg + g + 32);
            pv0 = *(const bf16x8*)(Vg + g);
            pv1 = *(const bf16x8*)(Vg + g + 32);
        }

        if (t == t0)
            qtile_step<true >(qf, Ks[cur], VsT[cur], Ps[w],
                              t * 64, q0 + w * 16, quad, l16, l, O);
        else
            qtile_step<false>(qf, Ks[cur], VsT[cur], Ps[w],
                              t * 64, q0 + w * 16, quad, l16, l, O);

        if (havenext) {   // stage tile t+1 into the other buffer, ONE barrier
            const int nb = cur ^ 1;
            *(bf16x8*)&Ks[nb][skey][sseg]      = pk0;
            *(bf16x8*)&Ks[nb][skey][sseg + 32] = pk1;
            #pragma unroll
            for (int e = 0; e < 8; ++e) {
                VsT[nb][sseg + e][pkey]      = pv0[e];
                VsT[nb][sseg + 32 + e][pkey] = pv1[e];
            }
            __syncthreads();
        }
    }

    // 16-lane reduction of l, then normalize + store
    #pragma unroll
    for (int off = 1; off < 16; off <<= 1)
        #pragma unroll
        for (int reg = 0; reg < 4; ++reg)
            l[reg] += __shfl_xor(l[reg], off, 64);
    #pragma unroll
    for (int reg = 0; reg < 4; ++reg) l[reg] = 1.0f / l[reg];
    #pragma unroll
    for (int nt = 0; nt < 4; ++nt)
        #pragma unroll
        for (int reg = 0; reg < 4; ++reg) {
            const size_t row = rb + q0 + w * 16 + quad * 4 + reg;
            CTX[row * Dc + cb + nt * 16 + l16] = f2bs(O[nt][reg] * l[reg]);
        }
}

// ---------------------------------------------------------------------------
// Row S-1 fully masked: reference softmax of all-(-1e9) is exactly uniform
// 1/S -> ctx = mean_j V[b,j,h,:]. Overwrites attn's placeholder.
// ---------------------------------------------------------------------------
__global__ __launch_bounds__(256) void vmean(const short* __restrict__ V,
                                             short* __restrict__ CTX)
{
    const int h = blockIdx.x, b = blockIdx.y;
    const int t = threadIdx.x;
    const int dh = t & 63, ck = t >> 6;      // 4 chunks of 512 keys
    float s = 0.f;
    const short* vp = V + ((size_t)b * Sc + ck * 512) * Dc + h * DHc + dh;
    for (int j = 0; j < 512; ++j) s += bs2f(vp[(size_t)j * Dc]);
    __shared__ float red[4][64];
    red[ck][dh] = s;
    __syncthreads();
    if (ck == 0) {
        const float tot = (red[0][dh] + red[1][dh] + red[2][dh] + red[3][dh]) * (1.f / Sc);
        CTX[((size_t)b * Sc + Sc - 1) * Dc + h * DHc + dh] = f2bs(tot);
    }
}

// ---------------------------------------------------------------------------
// out = LayerNorm(x + attn_out) * gamma + beta; x f32, AO bf16, out f32
// ---------------------------------------------------------------------------
__global__ __launch_bounds__(256, 4) void resid_ln(
    const float* __restrict__ X, const short* __restrict__ AO,
    const float* __restrict__ gamma, const float* __restrict__ beta,
    float* __restrict__ out)
{
    const int r = blockIdx.x;
    const int t = threadIdx.x;
    const size_t base = (size_t)r * Dc + t * 4;

    const float4 x4 = *(const float4*)(X + base);
    const ushort4 a4 = *(const ushort4*)(AO + base);
    float y[4];
    y[0] = x4.x + bs2f(a4.x);
    y[1] = x4.y + bs2f(a4.y);
    y[2] = x4.z + bs2f(a4.z);
    y[3] = x4.w + bs2f(a4.w);

    float s  = y[0] + y[1] + y[2] + y[3];
    float s2 = y[0]*y[0] + y[1]*y[1] + y[2]*y[2] + y[3]*y[3];
    #pragma unroll
    for (int off = 1; off < 64; off <<= 1) {
        s  += __shfl_xor(s,  off, 64);
        s2 += __shfl_xor(s2, off, 64);
    }
    __shared__ float red[8];
    const int w = t >> 6;
    if ((t & 63) == 0) { red[w] = s; red[4 + w] = s2; }
    __syncthreads();
    s  = red[0] + red[1] + red[2] + red[3];
    s2 = red[4] + red[5] + red[6] + red[7];

    const float mu   = s * (1.0f / Dc);
    const float rstd = rsqrtf(s2 * (1.0f / Dc) - mu * mu + 1e-6f);

    const float4 g4 = *(const float4*)(gamma + t * 4);
    const float4 b4 = *(const float4*)(beta  + t * 4);
    float4 o;
    o.x = (y[0] - mu) * rstd * g4.x + b4.x;
    o.y = (y[1] - mu) * rstd * g4.y + b4.y;
    o.z = (y[2] - mu) * rstd * g4.z + b4.z;
    o.w = (y[3] - mu) * rstd * g4.w + b4.w;
    *(float4*)(out + base) = o;
}

// ---------------------------------------------------------------------------
extern "C" void kernel_launch(void* const* d_in, const int* in_sizes, int n_in,
                              void* d_out, int out_size, void* d_ws, size_t ws_size,
                              hipStream_t stream)
{
    (void)in_sizes; (void)n_in; (void)out_size; (void)ws_size;
    const float* x     = (const float*)d_in[0];
    const float* Wq    = (const float*)d_in[1];
    const float* bq    = (const float*)d_in[2];
    const float* Wk    = (const float*)d_in[3];
    const float* bk    = (const float*)d_in[4];
    const float* Wv    = (const float*)d_in[5];
    const float* bv    = (const float*)d_in[6];
    const float* Wo    = (const float*)d_in[7];
    const float* bo    = (const float*)d_in[8];
    const float* gamma = (const float*)d_in[9];
    const float* beta  = (const float*)d_in[10];
    float* out = (float*)d_out;

    const size_t matN = (size_t)BS * Dc;       // 4,194,304
    const size_t wN   = (size_t)Dc * Dc;       // 1,048,576
    short* xb = (short*)d_ws;                  // 8 MB
    short* WT = xb + matN;                     // 8 MB (4 transposed weights)
    short* Qb = WT + 4 * wN;                   // 8 MB
    short* Kb = Qb + matN;                     // 8 MB
    short* Vb = Kb + matN;                     // 8 MB
    short* Cx = Vb + matN;                     // 8 MB
    short* AO = Qb;                            // Q dead after attention

    cast_x<<<matN / 1024, 256, 0, stream>>>(x, xb);

    dim3 gt(16, 16, 4);
    transpose_cast<<<gt, 256, 0, stream>>>(Wq, Wk, Wv, Wo, WT);

    dim3 gq(Dc / 128, BS / 128, 3);            // (8, 32, 3)
    gemm_bt<<<gq, 256, 0, stream>>>(xb, WT, bq, bk, bv, Qb);

    dim3 ga(32, Hc, Bc);                       // 1024 blocks, XCD-remapped inside
    attn_mfma<<<ga, 256, 0, stream>>>(Qb, Kb, Vb, Cx);

    dim3 gv(Hc, Bc);
    vmean<<<gv, 256, 0, stream>>>(Vb, Cx);     // fix up row S-1 (uniform softmax)

    dim3 go(Dc / 128, BS / 128, 1);
    gemm_bt<<<go, 256, 0, stream>>>(Cx, WT + 3 * wN, bo, bo, bo, AO);

    resid_ln<<<BS, 256, 0, stream>>>(x, AO, gamma, beta, out);
}

// Round 5
// 219.116 us; speedup vs baseline: 1.4481x; 1.0902x over previous
//
#include <hip/hip_runtime.h>
#include <hip/hip_bf16.h>

typedef __hip_bfloat16 bf16;
typedef __attribute__((ext_vector_type(8))) short bf16x8;   // 8 bf16 = 4 VGPRs
typedef __attribute__((ext_vector_type(4))) float f32x4;

constexpr int Bc  = 2;
constexpr int Sc  = 2048;
constexpr int Dc  = 1024;
constexpr int Hc  = 16;
constexpr int DHc = 64;
constexpr int BS  = Bc * Sc;   // 4096 rows
constexpr int NT  = Sc / 64;   // 32 key tiles

__device__ __forceinline__ float bs2f(unsigned short u) {
    union { unsigned int i; float f; } v; v.i = ((unsigned int)u) << 16; return v.f;
}
__device__ __forceinline__ short f2bs(float x) {
    bf16 h = __float2bfloat16(x);
    return *reinterpret_cast<short*>(&h);
}

// async global->LDS, 16B per lane. LDS dest is wave-uniform base + lane*16.
typedef const __attribute__((address_space(1))) unsigned int* as1_u32p;
typedef __attribute__((address_space(3))) unsigned int* as3_u32p;
__device__ __forceinline__ void gl_lds16(const void* g, void* l) {
    __builtin_amdgcn_global_load_lds((as1_u32p)g, (as3_u32p)l, 16, 0, 0);
}

// ---------------------------------------------------------------------------
// cast x (f32) -> bf16, same layout
// ---------------------------------------------------------------------------
__global__ __launch_bounds__(256) void cast_x(const float* __restrict__ in,
                                              short* __restrict__ out) {
    const int i = (blockIdx.x * 256 + threadIdx.x) * 4;
    const float4 v = *(const float4*)(in + i);
    ushort4 o;
    o.x = (unsigned short)f2bs(v.x);
    o.y = (unsigned short)f2bs(v.y);
    o.z = (unsigned short)f2bs(v.z);
    o.w = (unsigned short)f2bs(v.w);
    *(ushort4*)(out + i) = o;
}

// ---------------------------------------------------------------------------
// transpose + cast: in f32 [1024 k][1024 n] -> out bf16 [n][k].  z picks W.
// ---------------------------------------------------------------------------
__global__ __launch_bounds__(256) void transpose_cast(
    const float* __restrict__ w0, const float* __restrict__ w1,
    const float* __restrict__ w2, const float* __restrict__ w3,
    short* __restrict__ outbase)
{
    __shared__ float T[64][65];
    const int z = blockIdx.z;
    const float* in = (z == 0) ? w0 : (z == 1) ? w1 : (z == 2) ? w2 : w3;
    short* out = outbase + (size_t)z * 1024 * 1024;
    const int k0 = blockIdx.x * 64, n0 = blockIdx.y * 64;
    const int t = threadIdx.x;
    #pragma unroll
    for (int it = 0; it < 4; ++it) {
        const int s = it * 256 + t;
        const int r = s >> 4, c = (s & 15) * 4;
        *(float4*)&T[r][c] = *(const float4*)(in + (size_t)(k0 + r) * 1024 + n0 + c);
    }
    __syncthreads();
    #pragma unroll
    for (int it = 0; it < 4; ++it) {
        const int s = it * 256 + t;
        const int rr = s >> 4, cc = (s & 15) * 4;   // rr: n-local, cc: k-local
        ushort4 o;
        o.x = (unsigned short)f2bs(T[cc + 0][rr]);
        o.y = (unsigned short)f2bs(T[cc + 1][rr]);
        o.z = (unsigned short)f2bs(T[cc + 2][rr]);
        o.w = (unsigned short)f2bs(T[cc + 3][rr]);
        *(ushort4*)(out + (size_t)(n0 + rr) * 1024 + k0 + cc) = o;
    }
}

// ---------------------------------------------------------------------------
// MFMA GEMM (m97 structure): C[z] = A @ BT[z]^T + bias[z]
// 128x128 tile, BK=64, 256 thr = 4 waves of 64x64.
// ---------------------------------------------------------------------------
__global__ __launch_bounds__(256, 3) void gemm_bt(
    const short* __restrict__ A, const short* __restrict__ BTbase,
    const float* __restrict__ b0, const float* __restrict__ b1,
    const float* __restrict__ b2, short* __restrict__ Cbase)
{
    __shared__ __align__(16) short As[128 * 64];
    __shared__ __align__(16) short Bs[128 * 64];

    const int z = blockIdx.z;
    const short* BT = BTbase + (size_t)z * 1024 * 1024;
    const float* bias = (z == 0) ? b0 : (z == 1) ? b1 : b2;
    short* C = Cbase + (size_t)z * BS * Dc;

    const int t = threadIdx.x;
    const int lane = t & 63, w = t >> 6;
    const int quad = lane >> 4, l16 = lane & 15;
    const int wm = (w & 1) * 64, wn = (w >> 1) * 64;
    const int row0 = blockIdx.y * 128;
    const int col0 = blockIdx.x * 128;
    const int sw = l16 & 7;   // fragment-read swizzle key (row & 7)

    f32x4 acc[4][4] = {};

    for (int kt = 0; kt < 1024; kt += 64) {
        __syncthreads();
        #pragma unroll
        for (int i = 0; i < 4; ++i) {
            const int f = i * 256 + t;            // 16B slot index 0..1023
            const int r = f >> 3;                 // tile row 0..127
            const int g = (f & 7) ^ (r & 7);      // swizzled global seg
            short* lb = &As[(i * 256 + w * 64) * 8];   // wave-uniform base
            gl_lds16(A + (size_t)(row0 + r) * 1024 + kt + g * 8, lb);
            short* lb2 = &Bs[(i * 256 + w * 64) * 8];
            gl_lds16(BT + (size_t)(col0 + r) * 1024 + kt + g * 8, lb2);
        }
        __syncthreads();   // drains vmcnt before use
        #pragma unroll
        for (int ks = 0; ks < 2; ++ks) {
            bf16x8 av[4], bv[4];
            #pragma unroll
            for (int mt = 0; mt < 4; ++mt) {
                const int r = wm + mt * 16 + l16;
                av[mt] = *(const bf16x8*)&As[r * 64 + ((ks * 4 + quad) ^ sw) * 8];
            }
            #pragma unroll
            for (int nt = 0; nt < 4; ++nt) {
                const int r = wn + nt * 16 + l16;
                bv[nt] = *(const bf16x8*)&Bs[r * 64 + ((ks * 4 + quad) ^ sw) * 8];
            }
            #pragma unroll
            for (int mt = 0; mt < 4; ++mt)
                #pragma unroll
                for (int nt = 0; nt < 4; ++nt)
                    acc[mt][nt] = __builtin_amdgcn_mfma_f32_16x16x32_bf16(
                        av[mt], bv[nt], acc[mt][nt], 0, 0, 0);
        }
    }

    float bvv[4];
    #pragma unroll
    for (int nt = 0; nt < 4; ++nt) bvv[nt] = bias[col0 + wn + nt * 16 + l16];
    #pragma unroll
    for (int mt = 0; mt < 4; ++mt)
        #pragma unroll
        for (int reg = 0; reg < 4; ++reg) {
            const size_t row = row0 + wm + mt * 16 + quad * 4 + reg;
            #pragma unroll
            for (int nt = 0; nt < 4; ++nt) {
                const int col = col0 + wn + nt * 16 + l16;
                C[row * 1024 + col] = f2bs(acc[mt][nt][reg] + bvv[nt]);
            }
        }
}

// ---------------------------------------------------------------------------
// Key permutation pi(k) = (k&15)*4 + (k>>4), applied identically to the key
// axis of P and of VsT (sum over k is order-agnostic). Under pi, a thread's
// 4 P-values per output row become phys cols 4*l16+{0..3} -> one
// ds_write_b64 per row + packed cvt instead of 16 b16 writes + 16 RNE chains.
// ---------------------------------------------------------------------------

// softmax(step) + PV for one 16-row q-fragment vs a staged 64-key tile.
// DIAG: only the diagonal tile applies the strict-upper (col > row) mask.
// Layouts (HW-validated): A-frag A[m=l16][k=quad*8+j]; B-frag
// B[k=quad*8+j][n=l16]; C/D row=quad*4+reg, col=l16.
template<bool DIAG>
__device__ __forceinline__ void qtile_step(
    const bf16x8 (&qf)[2],
    const short (&Ks)[64][72], const short (&VsT)[64][72],
    short (&Psw)[16][72],
    const int k0, const int row_base,
    const int quad, const int l16,
    float (&l)[4], f32x4 (&O)[4])
{
    bf16x8 kf[2][4];
    #pragma unroll
    for (int ks = 0; ks < 2; ++ks)
        #pragma unroll
        for (int nt = 0; nt < 4; ++nt)
            kf[ks][nt] = *(const bf16x8*)&Ks[nt * 16 + l16][ks * 32 + quad * 8];

    f32x4 S[4] = {};
    #pragma unroll
    for (int ks = 0; ks < 2; ++ks)
        #pragma unroll
        for (int nt = 0; nt < 4; ++nt)
            S[nt] = __builtin_amdgcn_mfma_f32_16x16x32_bf16(qf[ks], kf[ks][nt], S[nt], 0, 0, 0);

    // exp(s/8) == exp2(s * 0.125*log2e); clamp 115.4 == old exp(<=80); mask
    // -126 -> 2^-126 ~= old exp(-87).
    #pragma unroll
    for (int nt = 0; nt < 4; ++nt) {
        #pragma unroll
        for (int reg = 0; reg < 4; ++reg) {
            float s = fminf(S[nt][reg] * 0.18033688f, 115.4f);
            if (DIAG) {
                const int col = k0 + nt * 16 + l16;
                const int row = row_base + quad * 4 + reg;
                s = (col > row) ? s : -126.0f;
            }
            const float p = exp2f(s);
            S[nt][reg] = p;
            l[reg] += p;
        }
    }

    // publish P: per output row, pack 4 values (phys cols 4*l16+0..3) -> b64
    #pragma unroll
    for (int reg = 0; reg < 4; ++reg) {
        const __hip_bfloat162 lo = __float22bfloat162_rn(make_float2(S[0][reg], S[1][reg]));
        const __hip_bfloat162 hi = __float22bfloat162_rn(make_float2(S[2][reg], S[3][reg]));
        uint2 u;
        u.x = *reinterpret_cast<const unsigned int*>(&lo);
        u.y = *reinterpret_cast<const unsigned int*>(&hi);
        *(uint2*)&Psw[quad * 4 + reg][l16 * 4] = u;
    }

    #pragma unroll
    for (int ks = 0; ks < 2; ++ks) {
        const bf16x8 pf = *(const bf16x8*)&Psw[l16][ks * 32 + quad * 8];
        #pragma unroll
        for (int nt = 0; nt < 4; ++nt) {
            const bf16x8 vf = *(const bf16x8*)&VsT[nt * 16 + l16][ks * 32 + quad * 8];
            O[nt] = __builtin_amdgcn_mfma_f32_16x16x32_bf16(pf, vf, O[nt], 0, 0, 0);
        }
    }
}

// ---------------------------------------------------------------------------
// Key-split MFMA flash attention, strict-upper mask (attend j > i).
// 512 blocks x 512 thr = 8 waves. Wave-group g = w>>2 (4 waves = 64 q-rows
// each): group 0 processes key tiles myq, myq+2, ...; group 1 processes
// myq+1, myq+3, ... -> sequential chain HALVES (<=16 rounds per q-tile).
// Each block runs q-tile p then 31-p: rounds/block = ceil((32-p)/2) +
// ceil((p+1)/2) = 17 for EVERY p -> per-block work exactly uniform (fixes
// R4's per-CU imbalance under stride-32 CU assignment).
// Each group single-buffers its own K/V tile (72-pad layouts, pi-permuted
// V); register prefetch of tile t+2 issues before compute; 2 barriers/round.
// Partial (O,l) merged across groups through LDS once per phase (plain add:
// no max subtraction in this softmax). LDS 54KB -> 2 blocks/CU = 16
// waves/CU (2x R2). XCD remap kept (FETCH 120->12MB in R4): each XCD owns
// 4 complete (b,h) groups, working set ~2MB in its private L2.
// Row S-1 (fully masked -> reference uniform softmax) fixed by vmean.
// ---------------------------------------------------------------------------
__global__ __launch_bounds__(512, 4) void attn_mfma(
    const short* __restrict__ Qg, const short* __restrict__ Kg,
    const short* __restrict__ Vg, short* __restrict__ CTX)
{
    __shared__ __align__(16) short Ks [2][64][72];   // [group][key][d]
    __shared__ __align__(16) short VsT[2][64][72];   // [group][d][pi(key)]
    __shared__ __align__(16) short Ps[8][16][72];    // per-wave P scratch; aliased
                                                     // as merge area in epilogue
    float* omrg = (float*)&Ps[0][0][0];              // [64 rows][65] f32 (16640 B)
    float* lmrg = omrg + 64 * 65;                    // [64 rows] f32 (256 B)

    const int tid  = threadIdx.x;
    const int lane = tid & 63, w = tid >> 6;         // w 0..7
    const int quad = lane >> 4, l16 = lane & 15;
    const int g  = w >> 2;                           // key-parity group
    const int wq = w & 3;                            // 16-row slice

    // XCD-locality remap (bijective, 512 % 8 == 0): XCD x owns r_ in
    // [64x, 64x+64) = all 16 pairs of 4 (b,h) groups.
    const int f  = blockIdx.x + 16 * blockIdx.y + 256 * blockIdx.z;  // 0..511
    const int r_ = (f & 7) * 64 + (f >> 3);
    const int p  = r_ & 15;
    const int h  = (r_ >> 4) & 15;
    const int b  = r_ >> 8;
    const size_t rb = (size_t)b * Sc;
    const int cb = h * DHc;

    // staging role: thread covers (skey, 32B slot) of its group's tile
    const int tid8  = tid & 255;
    const int skey  = tid8 >> 2;
    const int sslot = (tid8 & 3) * 16;
    const int pkey  = ((skey & 15) << 2) | (skey >> 4);   // pi(skey)

    #pragma unroll 1
    for (int ph = 0; ph < 2; ++ph) {
        const int myq = ph ? (NT - 1 - p) : p;
        const int n   = NT - myq;
        const int c0  = (n + 1) >> 1;     // group-0 tile count (rounds R)
        const int c1  = n >> 1;           // group-1 tile count
        const int cg  = g ? c1 : c0;
        const int R   = c0;
        const int q0  = myq * 64;

        // Q fragment for this wave's 16 rows
        bf16x8 qf[2];
        {
            const short* qp = Qg + (rb + q0 + wq * 16 + l16) * (size_t)Dc + cb + quad * 8;
            qf[0] = *(const bf16x8*)(qp);
            qf[1] = *(const bf16x8*)(qp + 32);
        }
        float l[4] = {};
        f32x4 O[4] = {};

        // prologue: stage this group's first tile (myq + g)
        if (cg > 0) {
            const size_t ga = (rb + (myq + g) * 64 + skey) * (size_t)Dc + cb + sslot;
            const bf16x8 k0v = *(const bf16x8*)(Kg + ga);
            const bf16x8 k1v = *(const bf16x8*)(Kg + ga + 8);
            const bf16x8 v0v = *(const bf16x8*)(Vg + ga);
            const bf16x8 v1v = *(const bf16x8*)(Vg + ga + 8);
            *(bf16x8*)&Ks[g][skey][sslot]     = k0v;
            *(bf16x8*)&Ks[g][skey][sslot + 8] = k1v;
            #pragma unroll
            for (int e = 0; e < 8; ++e) {
                VsT[g][sslot + e][pkey]     = v0v[e];
                VsT[g][sslot + 8 + e][pkey] = v1v[e];
            }
        }
        __syncthreads();

        for (int i = 0; i < R; ++i) {
            const bool pre = (i + 1 < cg);
            bf16x8 pk0, pk1, pv0, pv1;
            if (pre) {   // register prefetch of tile t+2 for this group
                const size_t ga = (rb + (myq + g + 2 * (i + 1)) * 64 + skey) * (size_t)Dc + cb + sslot;
                pk0 = *(const bf16x8*)(Kg + ga);
                pk1 = *(const bf16x8*)(Kg + ga + 8);
                pv0 = *(const bf16x8*)(Vg + ga);
                pv1 = *(const bf16x8*)(Vg + ga + 8);
            }

            if (i < cg) {
                const int t = myq + g + 2 * i;
                if (i == 0 && g == 0)
                    qtile_step<true >(qf, Ks[0], VsT[0], Ps[w],
                                      t * 64, q0 + wq * 16, quad, l16, l, O);
                else
                    qtile_step<false>(qf, Ks[g], VsT[g], Ps[w],
                                      t * 64, q0 + wq * 16, quad, l16, l, O);
            }

            if (i + 1 < R) {   // not last round: publish next tiles
                __syncthreads();   // all reads of Ks/VsT done
                if (pre) {
                    *(bf16x8*)&Ks[g][skey][sslot]     = pk0;
                    *(bf16x8*)&Ks[g][skey][sslot + 8] = pk1;
                    #pragma unroll
                    for (int e = 0; e < 8; ++e) {
                        VsT[g][sslot + e][pkey]     = pv0[e];
                        VsT[g][sslot + 8 + e][pkey] = pv1[e];
                    }
                }
                __syncthreads();   // writes visible
            }
        }

        // row-sum reduction of l over the 16 key-columns (within group)
        #pragma unroll
        for (int off = 1; off < 16; off <<= 1)
            #pragma unroll
            for (int reg = 0; reg < 4; ++reg)
                l[reg] += __shfl_xor(l[reg], off, 64);

        // merge group partials (plain add; Ps aliased as omrg/lmrg)
        __syncthreads();   // all compute (incl. Ps reads) done
        if (g == 1) {
            #pragma unroll
            for (int nt = 0; nt < 4; ++nt)
                #pragma unroll
                for (int reg = 0; reg < 4; ++reg)
                    omrg[(wq * 16 + quad * 4 + reg) * 65 + nt * 16 + l16] = O[nt][reg];
            if (l16 == 0)
                #pragma unroll
                for (int reg = 0; reg < 4; ++reg)
                    lmrg[wq * 16 + quad * 4 + reg] = l[reg];
        }
        __syncthreads();
        if (g == 0) {
            #pragma unroll
            for (int reg = 0; reg < 4; ++reg) {
                const int row = wq * 16 + quad * 4 + reg;
                const float inv = 1.0f / (l[reg] + lmrg[row]);
                #pragma unroll
                for (int nt = 0; nt < 4; ++nt) {
                    const float o = O[nt][reg] + omrg[row * 65 + nt * 16 + l16];
                    CTX[(rb + q0 + row) * Dc + cb + nt * 16 + l16] = f2bs(o * inv);
                }
            }
        }
        // next phase's prologue barrier orders omrg reads vs Ps reuse
    }
}

// ---------------------------------------------------------------------------
// Row S-1 fully masked: reference softmax of all-(-1e9) is exactly uniform
// 1/S -> ctx = mean_j V[b,j,h,:]. Overwrites attn's placeholder.
// ---------------------------------------------------------------------------
__global__ __launch_bounds__(256) void vmean(const short* __restrict__ V,
                                             short* __restrict__ CTX)
{
    const int h = blockIdx.x, b = blockIdx.y;
    const int t = threadIdx.x;
    const int dh = t & 63, ck = t >> 6;      // 4 chunks of 512 keys
    float s = 0.f;
    const short* vp = V + ((size_t)b * Sc + ck * 512) * Dc + h * DHc + dh;
    for (int j = 0; j < 512; ++j) s += bs2f(vp[(size_t)j * Dc]);
    __shared__ float red[4][64];
    red[ck][dh] = s;
    __syncthreads();
    if (ck == 0) {
        const float tot = (red[0][dh] + red[1][dh] + red[2][dh] + red[3][dh]) * (1.f / Sc);
        CTX[((size_t)b * Sc + Sc - 1) * Dc + h * DHc + dh] = f2bs(tot);
    }
}

// ---------------------------------------------------------------------------
// out = LayerNorm(x + attn_out) * gamma + beta; x f32, AO bf16, out f32
// ---------------------------------------------------------------------------
__global__ __launch_bounds__(256, 4) void resid_ln(
    const float* __restrict__ X, const short* __restrict__ AO,
    const float* __restrict__ gamma, const float* __restrict__ beta,
    float* __restrict__ out)
{
    const int r = blockIdx.x;
    const int t = threadIdx.x;
    const size_t base = (size_t)r * Dc + t * 4;

    const float4 x4 = *(const float4*)(X + base);
    const ushort4 a4 = *(const ushort4*)(AO + base);
    float y[4];
    y[0] = x4.x + bs2f(a4.x);
    y[1] = x4.y + bs2f(a4.y);
    y[2] = x4.z + bs2f(a4.z);
    y[3] = x4.w + bs2f(a4.w);

    float s  = y[0] + y[1] + y[2] + y[3];
    float s2 = y[0]*y[0] + y[1]*y[1] + y[2]*y[2] + y[3]*y[3];
    #pragma unroll
    for (int off = 1; off < 64; off <<= 1) {
        s  += __shfl_xor(s,  off, 64);
        s2 += __shfl_xor(s2, off, 64);
    }
    __shared__ float red[8];
    const int w = t >> 6;
    if ((t & 63) == 0) { red[w] = s; red[4 + w] = s2; }
    __syncthreads();
    s  = red[0] + red[1] + red[2] + red[3];
    s2 = red[4] + red[5] + red[6] + red[7];

    const float mu   = s * (1.0f / Dc);
    const float rstd = rsqrtf(s2 * (1.0f / Dc) - mu * mu + 1e-6f);

    const float4 g4 = *(const float4*)(gamma + t * 4);
    const float4 b4 = *(const float4*)(beta  + t * 4);
    float4 o;
    o.x = (y[0] - mu) * rstd * g4.x + b4.x;
    o.y = (y[1] - mu) * rstd * g4.y + b4.y;
    o.z = (y[2] - mu) * rstd * g4.z + b4.z;
    o.w = (y[3] - mu) * rstd * g4.w + b4.w;
    *(float4*)(out + base) = o;
}

// ---------------------------------------------------------------------------
extern "C" void kernel_launch(void* const* d_in, const int* in_sizes, int n_in,
                              void* d_out, int out_size, void* d_ws, size_t ws_size,
                              hipStream_t stream)
{
    (void)in_sizes; (void)n_in; (void)out_size; (void)ws_size;
    const float* x     = (const float*)d_in[0];
    const float* Wq    = (const float*)d_in[1];
    const float* bq    = (const float*)d_in[2];
    const float* Wk    = (const float*)d_in[3];
    const float* bk    = (const float*)d_in[4];
    const float* Wv    = (const float*)d_in[5];
    const float* bv    = (const float*)d_in[6];
    const float* Wo    = (const float*)d_in[7];
    const float* bo    = (const float*)d_in[8];
    const float* gamma = (const float*)d_in[9];
    const float* beta  = (const float*)d_in[10];
    float* out = (float*)d_out;

    const size_t matN = (size_t)BS * Dc;       // 4,194,304
    const size_t wN   = (size_t)Dc * Dc;       // 1,048,576
    short* xb = (short*)d_ws;                  // 8 MB
    short* WT = xb + matN;                     // 8 MB (4 transposed weights)
    short* Qb = WT + 4 * wN;                   // 8 MB
    short* Kb = Qb + matN;                     // 8 MB
    short* Vb = Kb + matN;                     // 8 MB
    short* Cx = Vb + matN;                     // 8 MB
    short* AO = Qb;                            // Q dead after attention

    cast_x<<<matN / 1024, 256, 0, stream>>>(x, xb);

    dim3 gt(16, 16, 4);
    transpose_cast<<<gt, 256, 0, stream>>>(Wq, Wk, Wv, Wo, WT);

    dim3 gq(Dc / 128, BS / 128, 3);            // (8, 32, 3)
    gemm_bt<<<gq, 256, 0, stream>>>(xb, WT, bq, bk, bv, Qb);

    dim3 ga(16, 16, 2);                        // 512 blocks, XCD-remapped inside
    attn_mfma<<<ga, 512, 0, stream>>>(Qb, Kb, Vb, Cx);

    dim3 gv(Hc, Bc);
    vmean<<<gv, 256, 0, stream>>>(Vb, Cx);     // fix up row S-1 (uniform softmax)

    dim3 go(Dc / 128, BS / 128, 1);
    gemm_bt<<<go, 256, 0, stream>>>(Cx, WT + 3 * wN, bo, bo, bo, AO);

    resid_ln<<<BS, 256, 0, stream>>>(x, AO, gamma, beta, out);
}

// Round 6
// 218.934 us; speedup vs baseline: 1.4493x; 1.0008x over previous
//
#include <hip/hip_runtime.h>
#include <hip/hip_bf16.h>

typedef __hip_bfloat16 bf16;
typedef __attribute__((ext_vector_type(8))) short bf16x8;   // 8 bf16 = 4 VGPRs
typedef __attribute__((ext_vector_type(4))) float f32x4;

constexpr int Bc  = 2;
constexpr int Sc  = 2048;
constexpr int Dc  = 1024;
constexpr int Hc  = 16;
constexpr int DHc = 64;
constexpr int BS  = Bc * Sc;   // 4096 rows
constexpr int NT  = Sc / 64;   // 32 key tiles

__device__ __forceinline__ float bs2f(unsigned short u) {
    union { unsigned int i; float f; } v; v.i = ((unsigned int)u) << 16; return v.f;
}
__device__ __forceinline__ short f2bs(float x) {
    bf16 h = __float2bfloat16(x);
    return *reinterpret_cast<short*>(&h);
}

// async global->LDS, 16B per lane. LDS dest is wave-uniform base + lane*16.
typedef const __attribute__((address_space(1))) unsigned int* as1_u32p;
typedef __attribute__((address_space(3))) unsigned int* as3_u32p;
__device__ __forceinline__ void gl_lds16(const void* g, void* l) {
    __builtin_amdgcn_global_load_lds((as1_u32p)g, (as3_u32p)l, 16, 0, 0);
}

// ---------------------------------------------------------------------------
// cast x (f32) -> bf16, same layout
// ---------------------------------------------------------------------------
__global__ __launch_bounds__(256) void cast_x(const float* __restrict__ in,
                                              short* __restrict__ out) {
    const int i = (blockIdx.x * 256 + threadIdx.x) * 4;
    const float4 v = *(const float4*)(in + i);
    ushort4 o;
    o.x = (unsigned short)f2bs(v.x);
    o.y = (unsigned short)f2bs(v.y);
    o.z = (unsigned short)f2bs(v.z);
    o.w = (unsigned short)f2bs(v.w);
    *(ushort4*)(out + i) = o;
}

// ---------------------------------------------------------------------------
// transpose + cast: in f32 [1024 k][1024 n] -> out bf16 [n][k].  z picks W.
// ---------------------------------------------------------------------------
__global__ __launch_bounds__(256) void transpose_cast(
    const float* __restrict__ w0, const float* __restrict__ w1,
    const float* __restrict__ w2, const float* __restrict__ w3,
    short* __restrict__ outbase)
{
    __shared__ float T[64][65];
    const int z = blockIdx.z;
    const float* in = (z == 0) ? w0 : (z == 1) ? w1 : (z == 2) ? w2 : w3;
    short* out = outbase + (size_t)z * 1024 * 1024;
    const int k0 = blockIdx.x * 64, n0 = blockIdx.y * 64;
    const int t = threadIdx.x;
    #pragma unroll
    for (int it = 0; it < 4; ++it) {
        const int s = it * 256 + t;
        const int r = s >> 4, c = (s & 15) * 4;
        *(float4*)&T[r][c] = *(const float4*)(in + (size_t)(k0 + r) * 1024 + n0 + c);
    }
    __syncthreads();
    #pragma unroll
    for (int it = 0; it < 4; ++it) {
        const int s = it * 256 + t;
        const int rr = s >> 4, cc = (s & 15) * 4;   // rr: n-local, cc: k-local
        ushort4 o;
        o.x = (unsigned short)f2bs(T[cc + 0][rr]);
        o.y = (unsigned short)f2bs(T[cc + 1][rr]);
        o.z = (unsigned short)f2bs(T[cc + 2][rr]);
        o.w = (unsigned short)f2bs(T[cc + 3][rr]);
        *(ushort4*)(out + (size_t)(n0 + rr) * 1024 + k0 + cc) = o;
    }
}

// ---------------------------------------------------------------------------
// MFMA GEMM (m97 structure): C[z] = (A @ BT[z]^T + bias[z]) * (z==0 ? sc0 : 1)
// 128x128 tile, BK=64, 256 thr = 4 waves of 64x64.
// sc0 folds the attention softmax scale (0.125*log2e) into Q at no cost.
// ---------------------------------------------------------------------------
__global__ __launch_bounds__(256, 3) void gemm_bt(
    const short* __restrict__ A, const short* __restrict__ BTbase,
    const float* __restrict__ b0, const float* __restrict__ b1,
    const float* __restrict__ b2, short* __restrict__ Cbase,
    const float sc0)
{
    __shared__ __align__(16) short As[128 * 64];
    __shared__ __align__(16) short Bs[128 * 64];

    const int z = blockIdx.z;
    const short* BT = BTbase + (size_t)z * 1024 * 1024;
    const float* bias = (z == 0) ? b0 : (z == 1) ? b1 : b2;
    const float sc = (z == 0) ? sc0 : 1.0f;
    short* C = Cbase + (size_t)z * BS * Dc;

    const int t = threadIdx.x;
    const int lane = t & 63, w = t >> 6;
    const int quad = lane >> 4, l16 = lane & 15;
    const int wm = (w & 1) * 64, wn = (w >> 1) * 64;
    const int row0 = blockIdx.y * 128;
    const int col0 = blockIdx.x * 128;
    const int sw = l16 & 7;   // fragment-read swizzle key (row & 7)

    f32x4 acc[4][4] = {};

    for (int kt = 0; kt < 1024; kt += 64) {
        __syncthreads();
        #pragma unroll
        for (int i = 0; i < 4; ++i) {
            const int f = i * 256 + t;            // 16B slot index 0..1023
            const int r = f >> 3;                 // tile row 0..127
            const int g = (f & 7) ^ (r & 7);      // swizzled global seg
            short* lb = &As[(i * 256 + w * 64) * 8];   // wave-uniform base
            gl_lds16(A + (size_t)(row0 + r) * 1024 + kt + g * 8, lb);
            short* lb2 = &Bs[(i * 256 + w * 64) * 8];
            gl_lds16(BT + (size_t)(col0 + r) * 1024 + kt + g * 8, lb2);
        }
        __syncthreads();   // drains vmcnt before use
        #pragma unroll
        for (int ks = 0; ks < 2; ++ks) {
            bf16x8 av[4], bv[4];
            #pragma unroll
            for (int mt = 0; mt < 4; ++mt) {
                const int r = wm + mt * 16 + l16;
                av[mt] = *(const bf16x8*)&As[r * 64 + ((ks * 4 + quad) ^ sw) * 8];
            }
            #pragma unroll
            for (int nt = 0; nt < 4; ++nt) {
                const int r = wn + nt * 16 + l16;
                bv[nt] = *(const bf16x8*)&Bs[r * 64 + ((ks * 4 + quad) ^ sw) * 8];
            }
            #pragma unroll
            for (int mt = 0; mt < 4; ++mt)
                #pragma unroll
                for (int nt = 0; nt < 4; ++nt)
                    acc[mt][nt] = __builtin_amdgcn_mfma_f32_16x16x32_bf16(
                        av[mt], bv[nt], acc[mt][nt], 0, 0, 0);
        }
    }

    float bvv[4];
    #pragma unroll
    for (int nt = 0; nt < 4; ++nt) bvv[nt] = bias[col0 + wn + nt * 16 + l16];
    #pragma unroll
    for (int mt = 0; mt < 4; ++mt)
        #pragma unroll
        for (int reg = 0; reg < 4; ++reg) {
            const size_t row = row0 + wm + mt * 16 + quad * 4 + reg;
            #pragma unroll
            for (int nt = 0; nt < 4; ++nt) {
                const int col = col0 + wn + nt * 16 + l16;
                C[row * 1024 + col] = f2bs((acc[mt][nt][reg] + bvv[nt]) * sc);
            }
        }
}

// ---------------------------------------------------------------------------
// Key permutation pi(k) = (k&15)*4 + (k>>4), applied identically to the key
// axis of P and of VsT (sum over k is order-agnostic). Under pi, a thread's
// 4 P-values per output row become phys cols 4*l16+{0..3} -> one
// ds_write_b64 per row + packed cvt instead of 16 b16 writes + 16 RNE chains.
// ---------------------------------------------------------------------------

// softmax(step) + PV for one 16-row q-fragment vs a staged 64-key tile.
// Q is PRE-SCALED by 0.125*log2e in gemm_bt, so scores feed exp2 directly.
// DIAG: only the diagonal tile applies the strict-upper (col > row) mask.
// Layouts (HW-validated): A-frag A[m=l16][k=quad*8+j]; B-frag
// B[k=quad*8+j][n=l16]; C/D row=quad*4+reg, col=l16.
template<bool DIAG>
__device__ __forceinline__ void qtile_step(
    const bf16x8 (&qf)[2],
    const short (&Ks)[64][72], const short (&VsT)[64][72],
    short (&Psw)[16][72],
    const int k0, const int row_base,
    const int quad, const int l16,
    float (&l)[4], f32x4 (&O)[4])
{
    bf16x8 kf[2][4];
    #pragma unroll
    for (int ks = 0; ks < 2; ++ks)
        #pragma unroll
        for (int nt = 0; nt < 4; ++nt)
            kf[ks][nt] = *(const bf16x8*)&Ks[nt * 16 + l16][ks * 32 + quad * 8];

    f32x4 S[4] = {};
    __builtin_amdgcn_s_setprio(1);
    #pragma unroll
    for (int ks = 0; ks < 2; ++ks)
        #pragma unroll
        for (int nt = 0; nt < 4; ++nt)
            S[nt] = __builtin_amdgcn_mfma_f32_16x16x32_bf16(qf[ks], kf[ks][nt], S[nt], 0, 0, 0);
    __builtin_amdgcn_s_setprio(0);

    // clamp 115.4 == old exp(<=80); mask -126 -> 2^-126 ~= old exp(-87).
    #pragma unroll
    for (int nt = 0; nt < 4; ++nt) {
        #pragma unroll
        for (int reg = 0; reg < 4; ++reg) {
            float s = fminf(S[nt][reg], 115.4f);
            if (DIAG) {
                const int col = k0 + nt * 16 + l16;
                const int row = row_base + quad * 4 + reg;
                s = (col > row) ? s : -126.0f;
            }
            const float p = exp2f(s);
            S[nt][reg] = p;
            l[reg] += p;
        }
    }

    // publish P: per output row, pack 4 values (phys cols 4*l16+0..3) -> b64
    #pragma unroll
    for (int reg = 0; reg < 4; ++reg) {
        const __hip_bfloat162 lo = __float22bfloat162_rn(make_float2(S[0][reg], S[1][reg]));
        const __hip_bfloat162 hi = __float22bfloat162_rn(make_float2(S[2][reg], S[3][reg]));
        uint2 u;
        u.x = *reinterpret_cast<const unsigned int*>(&lo);
        u.y = *reinterpret_cast<const unsigned int*>(&hi);
        *(uint2*)&Psw[quad * 4 + reg][l16 * 4] = u;
    }

    __builtin_amdgcn_s_setprio(1);
    #pragma unroll
    for (int ks = 0; ks < 2; ++ks) {
        const bf16x8 pf = *(const bf16x8*)&Psw[l16][ks * 32 + quad * 8];
        #pragma unroll
        for (int nt = 0; nt < 4; ++nt) {
            const bf16x8 vf = *(const bf16x8*)&VsT[nt * 16 + l16][ks * 32 + quad * 8];
            O[nt] = __builtin_amdgcn_mfma_f32_16x16x32_bf16(pf, vf, O[nt], 0, 0, 0);
        }
    }
    __builtin_amdgcn_s_setprio(0);
}

// ---------------------------------------------------------------------------
// Independent-block MFMA flash attention, strict-upper mask (attend j > i).
// 1024 blocks x 256 thr (4 waves), ONE 64-row q-tile per block, single-
// buffered K/V (27.6KB LDS) -> exactly 4 resident blocks/CU, 16 waves/CU
// from INDEPENDENT barrier domains: while one block drains its barrier the
// other three compute (fixes R5's phase serialization: LDS 45% / VALU 37% /
// MFMA 12% taking turns).
// CU-balance: within an XCD, CU c receives locals {c,c+32,c+64,c+96}
// (stride-32 round-robin, established by R4's failure mode). j=loc>>5 picks
// the (b,h) within the XCD AND alternates heavy/light: myq = j odd ?
// 31-(loc&31) : (loc&31) -> per-CU tile total = 66, constant.
// XCD remap kept (FETCH 120->12MB): XCD x owns (b,h) in [4x,4x+4), working
// set ~3MB in its private L2.
// Staging = R2's conflict-free pattern (full 64-key pkey coverage; R5's
// 16-key variant was the +6.7M bank-conflict regression).
// Row S-1 (fully masked -> reference uniform softmax) fixed by vmean.
// ---------------------------------------------------------------------------
__global__ __launch_bounds__(256, 4) void attn_mfma(
    const short* __restrict__ Qg, const short* __restrict__ Kg,
    const short* __restrict__ Vg, short* __restrict__ CTX)
{
    __shared__ __align__(16) short Ks [64][72];   // [key][d]
    __shared__ __align__(16) short VsT[64][72];   // [d][pi(key)]
    __shared__ __align__(16) short Ps[4][16][72]; // per-wave P scratch

    const int tid  = threadIdx.x;
    const int lane = tid & 63, w = tid >> 6;         // w 0..3
    const int quad = lane >> 4, l16 = lane & 15;

    // XCD-locality remap + CU-balanced q map
    const int f   = blockIdx.x + 32 * blockIdx.y + 512 * blockIdx.z;  // 0..1023
    const int xcd = f & 7;
    const int loc = f >> 3;            // 0..127 within XCD
    const int j   = loc >> 5;          // 0..3: (b,h)-within-XCD + heavy/light alt
    const int lq  = loc & 31;
    const int myq = (j & 1) ? (NT - 1 - lq) : lq;
    const int bh  = xcd * 4 + j;       // 0..31
    const int h   = bh & 15;
    const int b   = bh >> 4;
    const size_t rb = (size_t)b * Sc;
    const int cb = h * DHc;

    const int t0 = myq;
    const int q0 = myq * 64;

    // Q fragment for this wave's 16 rows (pre-scaled by 0.125*log2e)
    bf16x8 qf[2];
    {
        const short* qp = Qg + (rb + q0 + w * 16 + l16) * (size_t)Dc + cb + quad * 8;
        qf[0] = *(const bf16x8*)(qp);
        qf[1] = *(const bf16x8*)(qp + 32);
    }
    float l[4] = {};
    f32x4 O[4] = {};

    // staging: 256 threads; thread stages key row skey, d-segs sseg & sseg+32
    const int skey = tid & 63, sseg = (tid >> 6) * 8;
    const int pkey = ((skey & 15) << 2) | (skey >> 4);   // pi(skey)

    {   // stage first tile t0
        const size_t g = (rb + t0 * 64 + skey) * (size_t)Dc + cb + sseg;
        const bf16x8 k0v = *(const bf16x8*)(Kg + g);
        const bf16x8 k1v = *(const bf16x8*)(Kg + g + 32);
        const bf16x8 v0v = *(const bf16x8*)(Vg + g);
        const bf16x8 v1v = *(const bf16x8*)(Vg + g + 32);
        *(bf16x8*)&Ks[skey][sseg]      = k0v;
        *(bf16x8*)&Ks[skey][sseg + 32] = k1v;
        #pragma unroll
        for (int e = 0; e < 8; ++e) {
            VsT[sseg + e][pkey]      = v0v[e];
            VsT[sseg + 32 + e][pkey] = v1v[e];
        }
    }
    __syncthreads();

    for (int t = t0; t < NT; ++t) {
        const bool havenext = (t + 1 < NT);
        bf16x8 pk0, pk1, pv0, pv1;
        if (havenext) {   // register prefetch of tile t+1 (issues before compute)
            const size_t g = (rb + (t + 1) * 64 + skey) * (size_t)Dc + cb + sseg;
            pk0 = *(const bf16x8*)(Kg + g);
            pk1 = *(const bf16x8*)(Kg + g + 32);
            pv0 = *(const bf16x8*)(Vg + g);
            pv1 = *(const bf16x8*)(Vg + g + 32);
        }

        if (t == t0)
            qtile_step<true >(qf, Ks, VsT, Ps[w],
                              t * 64, q0 + w * 16, quad, l16, l, O);
        else
            qtile_step<false>(qf, Ks, VsT, Ps[w],
                              t * 64, q0 + w * 16, quad, l16, l, O);

        if (havenext) {   // single-buffer overwrite: sync, write, sync
            __syncthreads();   // all waves done reading Ks/VsT
            *(bf16x8*)&Ks[skey][sseg]      = pk0;
            *(bf16x8*)&Ks[skey][sseg + 32] = pk1;
            #pragma unroll
            for (int e = 0; e < 8; ++e) {
                VsT[sseg + e][pkey]      = pv0[e];
                VsT[sseg + 32 + e][pkey] = pv1[e];
            }
            __syncthreads();   // writes visible
        }
    }

    // 16-lane reduction of l, then normalize + store
    #pragma unroll
    for (int off = 1; off < 16; off <<= 1)
        #pragma unroll
        for (int reg = 0; reg < 4; ++reg)
            l[reg] += __shfl_xor(l[reg], off, 64);
    #pragma unroll
    for (int reg = 0; reg < 4; ++reg) l[reg] = 1.0f / l[reg];
    #pragma unroll
    for (int nt = 0; nt < 4; ++nt)
        #pragma unroll
        for (int reg = 0; reg < 4; ++reg) {
            const size_t row = rb + q0 + w * 16 + quad * 4 + reg;
            CTX[row * Dc + cb + nt * 16 + l16] = f2bs(O[nt][reg] * l[reg]);
        }
}

// ---------------------------------------------------------------------------
// Row S-1 fully masked: reference softmax of all-(-1e9) is exactly uniform
// 1/S -> ctx = mean_j V[b,j,h,:]. Overwrites attn's placeholder.
// ---------------------------------------------------------------------------
__global__ __launch_bounds__(256) void vmean(const short* __restrict__ V,
                                             short* __restrict__ CTX)
{
    const int h = blockIdx.x, b = blockIdx.y;
    const int t = threadIdx.x;
    const int dh = t & 63, ck = t >> 6;      // 4 chunks of 512 keys
    float s = 0.f;
    const short* vp = V + ((size_t)b * Sc + ck * 512) * Dc + h * DHc + dh;
    for (int j = 0; j < 512; ++j) s += bs2f(vp[(size_t)j * Dc]);
    __shared__ float red[4][64];
    red[ck][dh] = s;
    __syncthreads();
    if (ck == 0) {
        const float tot = (red[0][dh] + red[1][dh] + red[2][dh] + red[3][dh]) * (1.f / Sc);
        CTX[((size_t)b * Sc + Sc - 1) * Dc + h * DHc + dh] = f2bs(tot);
    }
}

// ---------------------------------------------------------------------------
// out = LayerNorm(x + attn_out) * gamma + beta; x f32, AO bf16, out f32
// ---------------------------------------------------------------------------
__global__ __launch_bounds__(256, 4) void resid_ln(
    const float* __restrict__ X, const short* __restrict__ AO,
    const float* __restrict__ gamma, const float* __restrict__ beta,
    float* __restrict__ out)
{
    const int r = blockIdx.x;
    const int t = threadIdx.x;
    const size_t base = (size_t)r * Dc + t * 4;

    const float4 x4 = *(const float4*)(X + base);
    const ushort4 a4 = *(const ushort4*)(AO + base);
    float y[4];
    y[0] = x4.x + bs2f(a4.x);
    y[1] = x4.y + bs2f(a4.y);
    y[2] = x4.z + bs2f(a4.z);
    y[3] = x4.w + bs2f(a4.w);

    float s  = y[0] + y[1] + y[2] + y[3];
    float s2 = y[0]*y[0] + y[1]*y[1] + y[2]*y[2] + y[3]*y[3];
    #pragma unroll
    for (int off = 1; off < 64; off <<= 1) {
        s  += __shfl_xor(s,  off, 64);
        s2 += __shfl_xor(s2, off, 64);
    }
    __shared__ float red[8];
    const int w = t >> 6;
    if ((t & 63) == 0) { red[w] = s; red[4 + w] = s2; }
    __syncthreads();
    s  = red[0] + red[1] + red[2] + red[3];
    s2 = red[4] + red[5] + red[6] + red[7];

    const float mu   = s * (1.0f / Dc);
    const float rstd = rsqrtf(s2 * (1.0f / Dc) - mu * mu + 1e-6f);

    const float4 g4 = *(const float4*)(gamma + t * 4);
    const float4 b4 = *(const float4*)(beta  + t * 4);
    float4 o;
    o.x = (y[0] - mu) * rstd * g4.x + b4.x;
    o.y = (y[1] - mu) * rstd * g4.y + b4.y;
    o.z = (y[2] - mu) * rstd * g4.z + b4.z;
    o.w = (y[3] - mu) * rstd * g4.w + b4.w;
    *(float4*)(out + base) = o;
}

// ---------------------------------------------------------------------------
extern "C" void kernel_launch(void* const* d_in, const int* in_sizes, int n_in,
                              void* d_out, int out_size, void* d_ws, size_t ws_size,
                              hipStream_t stream)
{
    (void)in_sizes; (void)n_in; (void)out_size; (void)ws_size;
    const float* x     = (const float*)d_in[0];
    const float* Wq    = (const float*)d_in[1];
    const float* bq    = (const float*)d_in[2];
    const float* Wk    = (const float*)d_in[3];
    const float* bk    = (const float*)d_in[4];
    const float* Wv    = (const float*)d_in[5];
    const float* bv    = (const float*)d_in[6];
    const float* Wo    = (const float*)d_in[7];
    const float* bo    = (const float*)d_in[8];
    const float* gamma = (const float*)d_in[9];
    const float* beta  = (const float*)d_in[10];
    float* out = (float*)d_out;

    const size_t matN = (size_t)BS * Dc;       // 4,194,304
    const size_t wN   = (size_t)Dc * Dc;       // 1,048,576
    short* xb = (short*)d_ws;                  // 8 MB
    short* WT = xb + matN;                     // 8 MB (4 transposed weights)
    short* Qb = WT + 4 * wN;                   // 8 MB
    short* Kb = Qb + matN;                     // 8 MB
    short* Vb = Kb + matN;                     // 8 MB
    short* Cx = Vb + matN;                     // 8 MB
    short* AO = Qb;                            // Q dead after attention

    cast_x<<<matN / 1024, 256, 0, stream>>>(x, xb);

    dim3 gt(16, 16, 4);
    transpose_cast<<<gt, 256, 0, stream>>>(Wq, Wk, Wv, Wo, WT);

    dim3 gq(Dc / 128, BS / 128, 3);            // (8, 32, 3)
    gemm_bt<<<gq, 256, 0, stream>>>(xb, WT, bq, bk, bv, Qb, 0.18033688f);

    dim3 ga(32, 16, 2);                        // 1024 blocks, remapped inside
    attn_mfma<<<ga, 256, 0, stream>>>(Qb, Kb, Vb, Cx);

    dim3 gv(Hc, Bc);
    vmean<<<gv, 256, 0, stream>>>(Vb, Cx);     // fix up row S-1 (uniform softmax)

    dim3 go(Dc / 128, BS / 128, 1);
    gemm_bt<<<go, 256, 0, stream>>>(Cx, WT + 3 * wN, bo, bo, bo, AO, 1.0f);

    resid_ln<<<BS, 256, 0, stream>>>(x, AO, gamma, beta, out);
}